// Round 6
// baseline (423.185 us; speedup 1.0000x reference)
//
#include <hip/hip_runtime.h>
#include <math.h>

// ---------------- constants for this problem ----------------
#define S_LEN 2048
#define DM    1024
#define NH    16
#define DH    64
#define BATCH 2
#define MROWS 4096        // BATCH * S_LEN
#define LOG2E 1.44269504088896340736f

typedef __attribute__((ext_vector_type(8))) short short8;   // 8 x bf16 (4 VGPRs)
typedef __attribute__((ext_vector_type(4))) float f32x4;

// fp32 -> bf16 round-to-nearest-even (finite inputs)
__device__ __forceinline__ unsigned short f2bf(float f) {
    unsigned int u = __float_as_uint(f);
    u += 0x7FFFu + ((u >> 16) & 1u);
    return (unsigned short)(u >> 16);
}

// async global->LDS, 16B per lane; LDS dest = wave-uniform base + lane*16
__device__ __forceinline__ void gload16(const void* g, void* lds) {
    __builtin_amdgcn_global_load_lds((const __attribute__((address_space(1))) void*)g,
                                     (__attribute__((address_space(3))) void*)lds,
                                     16, 0, 0);
}

// ---------------- small prep kernels ----------------
__global__ void initflag_kernel(int* flag) {
    if (threadIdx.x == 0 && blockIdx.x == 0) *flag = 1;
}

__global__ __launch_bounds__(256) void convert3(
    const float* __restrict__ q, const float* __restrict__ k, const float* __restrict__ v,
    unsigned short* __restrict__ qb, unsigned short* __restrict__ kb, unsigned short* __restrict__ vb,
    int n4)
{
    int i = blockIdx.x * 256 + threadIdx.x;
    if (i >= n4) return;
    float4 a = ((const float4*)q)[i];
    float4 b = ((const float4*)k)[i];
    float4 c = ((const float4*)v)[i];
    ((ushort4*)qb)[i] = make_ushort4(f2bf(a.x), f2bf(a.y), f2bf(a.z), f2bf(a.w));
    ((ushort4*)kb)[i] = make_ushort4(f2bf(b.x), f2bf(b.y), f2bf(b.z), f2bf(b.w));
    ((ushort4*)vb)[i] = make_ushort4(f2bf(c.x), f2bf(c.y), f2bf(c.z), f2bf(c.w));
}

// transpose [R][C] fp32 slab -> [C][R] bf16 slab (slab = blockIdx.z * R * C for both)
__global__ __launch_bounds__(256) void transpose_bf16(
    const float* __restrict__ in, unsigned short* __restrict__ out, int R, int C)
{
    __shared__ float tile[32][33];
    const size_t slab = (size_t)blockIdx.z * R * C;
    const int r0 = blockIdx.x * 32;
    const int c0 = blockIdx.y * 32;
    const int tr = threadIdx.x >> 5;
    const int tc = threadIdx.x & 31;
#pragma unroll
    for (int j = 0; j < 32; j += 8)
        tile[tr + j][tc] = in[slab + (size_t)(r0 + tr + j) * C + c0 + tc];
    __syncthreads();
#pragma unroll
    for (int j = 0; j < 32; j += 8)
        out[slab + (size_t)(c0 + tr + j) * R + r0 + tc] = f2bf(tile[tc][tr + j]);
}

// mask[S*S] int32 -> bit per element; flag &= all-ones
__global__ __launch_bounds__(256) void maskbits_kernel(
    const int* __restrict__ mask, unsigned int* __restrict__ bits, int* __restrict__ flag)
{
    int widx = blockIdx.x * 256 + threadIdx.x;      // word index, 131072 total
    const int4* src = (const int4*)(mask + (size_t)widx * 32);
    unsigned int wb = 0;
#pragma unroll
    for (int j = 0; j < 8; ++j) {
        int4 vv = src[j];
        wb |= (vv.x != 0 ? 1u : 0u) << (4 * j);
        wb |= (vv.y != 0 ? 1u : 0u) << (4 * j + 1);
        wb |= (vv.z != 0 ? 1u : 0u) << (4 * j + 2);
        wb |= (vv.w != 0 ? 1u : 0u) << (4 * j + 3);
    }
    bits[widx] = wb;
    if (wb != 0xFFFFFFFFu) atomicAnd(flag, 0);
}

// ---------------- 128x128 bf16 GEMM (K=1024 fixed), m97-style ----------------
// A: [4096][1024] bf16 row-major (per z).  Bt: [1024 n][1024 k] bf16 (= W^T, per z).
// MODE 0: out = bf16, + bias[n], scattered to [B][H][S][64] head-major (per z).
// MODE 1: out = fp32 row-major [4096][1024] (d_out).
// LDS tiles are XOR-swizzled: element (row,kbyte) stored at (row*128+kbyte) ^ ((row&7)<<4);
// gload_lds writes linearly, so the SOURCE address is pre-unswizzled (rule #21).
template<int MODE>
__global__ __launch_bounds__(256) void gemm128(
    const unsigned short* __restrict__ Aall,
    const unsigned short* __restrict__ Btall,
    const float* __restrict__ bias0, const float* __restrict__ bias1, const float* __restrict__ bias2,
    void* __restrict__ outp)
{
    __shared__ __attribute__((aligned(16))) unsigned short Asm[128 * 64];
    __shared__ __attribute__((aligned(16))) unsigned short Bsm[128 * 64];
    char* AsmC = (char*)Asm;
    char* BsmC = (char*)Bsm;
    const int tid  = threadIdx.x;
    const int w    = tid >> 6;
    const int lane = tid & 63;
    const int m0 = blockIdx.y * 128;
    const int n0 = blockIdx.x * 128;
    const int z  = blockIdx.z;

    const char* Ac = (const char*)(Aall + (size_t)z * MROWS * DM);
    const char* Bc = (const char*)(Btall + (size_t)z * DM * DM);

    // staging: LDS linear byte L -> logical (row, kbyte) via inverse swizzle
    int arow[4], akof[4];
#pragma unroll
    for (int r = 0; r < 4; ++r) {
        int L = r * 4096 + tid * 16;
        int a = L ^ (((L >> 7) & 7) << 4);
        arow[r] = a >> 7;
        akof[r] = a & 127;
    }

    const int wr = (w >> 1) * 64;
    const int wc = (w & 1) * 64;
    int aaddr[4], baddr[4];
#pragma unroll
    for (int f = 0; f < 4; ++f) {
        int rr = wr + f * 16 + (lane & 15);
        aaddr[f] = (rr * 128 + ((lane >> 4) << 4)) ^ ((rr & 7) << 4);
        int rn = wc + f * 16 + (lane & 15);
        baddr[f] = (rn * 128 + ((lane >> 4) << 4)) ^ ((rn & 7) << 4);
    }

    f32x4 acc[4][4] = {};

    for (int kt = 0; kt < 16; ++kt) {
        __syncthreads();
#pragma unroll
        for (int r = 0; r < 4; ++r) {
            gload16(Ac + (size_t)(m0 + arow[r]) * (DM * 2) + kt * 128 + akof[r],
                    AsmC + r * 4096 + w * 1024);
            gload16(Bc + (size_t)(n0 + arow[r]) * (DM * 2) + kt * 128 + akof[r],
                    BsmC + r * 4096 + w * 1024);
        }
        __syncthreads();
#pragma unroll
        for (int ks = 0; ks < 2; ++ks) {
            short8 af[4], bf[4];
#pragma unroll
            for (int f = 0; f < 4; ++f) af[f] = *(const short8*)(AsmC + (aaddr[f] ^ (ks << 6)));
#pragma unroll
            for (int f = 0; f < 4; ++f) bf[f] = *(const short8*)(BsmC + (baddr[f] ^ (ks << 6)));
#pragma unroll
            for (int mf = 0; mf < 4; ++mf)
#pragma unroll
                for (int nf = 0; nf < 4; ++nf)
                    acc[mf][nf] = __builtin_amdgcn_mfma_f32_16x16x32_bf16(af[mf], bf[nf], acc[mf][nf], 0, 0, 0);
        }
    }

    if constexpr (MODE == 0) {
        const float* bias = (z == 0) ? bias0 : (z == 1) ? bias1 : bias2;
        unsigned short* out = ((unsigned short*)outp) + (size_t)z * MROWS * DM;
        float bv[4];
#pragma unroll
        for (int nf = 0; nf < 4; ++nf) bv[nf] = bias[n0 + wc + nf * 16 + (lane & 15)];
#pragma unroll
        for (int mf = 0; mf < 4; ++mf)
#pragma unroll
            for (int nf = 0; nf < 4; ++nf)
#pragma unroll
                for (int i = 0; i < 4; ++i) {
                    int grow = m0 + wr + mf * 16 + ((lane >> 4) << 2) + i;
                    int gcol = n0 + wc + nf * 16 + (lane & 15);
                    float val = acc[mf][nf][i] + bv[nf];
                    int b = grow >> 11, srow = grow & 2047, h = gcol >> 6, e = gcol & 63;
                    out[((size_t)(b * NH + h) * S_LEN + srow) * DH + e] = f2bf(val);
                }
    } else {
        float* out = (float*)outp;
#pragma unroll
        for (int mf = 0; mf < 4; ++mf)
#pragma unroll
            for (int nf = 0; nf < 4; ++nf)
#pragma unroll
                for (int i = 0; i < 4; ++i) {
                    int grow = m0 + wr + mf * 16 + ((lane >> 4) << 2) + i;
                    int gcol = n0 + wc + nf * 16 + (lane & 15);
                    out[(size_t)grow * DM + gcol] = acc[mf][nf][i];
                }
    }
}

// ---------------- flash attention ----------------
// grid (16 q-tiles, 32 bh).  4 waves x 32 q-rows each, KVBLK=64, D_HEAD=64.
// Q/K staged via gload_lds with pre-unswizzled source; V reg-transposed into a
// bank-spread layout; P round-trips through per-wave swizzled LDS (reuses Q region).
__global__ __launch_bounds__(256) void attn_kernel(
    const unsigned short* __restrict__ Qh, const unsigned short* __restrict__ Kh,
    const unsigned short* __restrict__ Vh, unsigned short* __restrict__ ctx,
    const unsigned int* __restrict__ mbits, const int* __restrict__ flag)
{
    __shared__ __attribute__((aligned(16))) char smem[16384 + 8192 + 8192];
    char* QP  = smem;             // 16KB: Q tile, then per-wave P buffers
    char* Ksm = smem + 16384;     // 8KB
    char* Vsm = smem + 24576;     // 8KB, transposed [d][t] with bank-spread XOR

    const int tid  = threadIdx.x;
    const int w    = tid >> 6;
    const int lane = tid & 63;
    const int q0 = blockIdx.x * 128;
    const int bh = blockIdx.y;

    const char* Qb = (const char*)(Qh + (size_t)bh * S_LEN * DH);
    const char* Kb = (const char*)(Kh + (size_t)bh * S_LEN * DH);
    const char* Vb = (const char*)(Vh + (size_t)bh * S_LEN * DH);

    // ---- stage Q tile (128 x 64 bf16 = 16KB), swizzled ----
#pragma unroll
    for (int r = 0; r < 4; ++r) {
        int L = r * 4096 + tid * 16;
        int a = L ^ (((L >> 7) & 7) << 4);
        gload16(Qb + (size_t)(q0 + (a >> 7)) * (DH * 2) + (a & 127), QP + r * 4096 + w * 1024);
    }
    __syncthreads();

    // ---- hoist Q fragments into registers ----
    short8 qf[2][2];
#pragma unroll
    for (int mf = 0; mf < 2; ++mf)
#pragma unroll
        for (int ks = 0; ks < 2; ++ks) {
            int arow = w * 32 + mf * 16 + (lane & 15);
            int a = arow * 128 + ks * 64 + ((lane >> 4) << 4);
            qf[mf][ks] = *(const short8*)(QP + (a ^ ((arow & 7) << 4)));
        }
    __syncthreads();  // all waves done with Q before P reuses the region

    const bool allones = (*flag) != 0;

    float mstate[2][4], lstate[2][4];
#pragma unroll
    for (int mf = 0; mf < 2; ++mf)
#pragma unroll
        for (int i = 0; i < 4; ++i) { mstate[mf][i] = -INFINITY; lstate[mf][i] = 0.f; }
    f32x4 o[2][4] = {};

    char* Pw = QP + w * 4096;   // per-wave P buffer (32 x 64 bf16, swizzled)

    for (int kv = 0; kv < 32; ++kv) {
        const int kv0 = kv * 64;
        __syncthreads();   // previous iteration's K/V reads complete

        // stage K (64 x 64 bf16 = 8KB), swizzled source
#pragma unroll
        for (int r = 0; r < 2; ++r) {
            int L = r * 4096 + tid * 16;
            int a = L ^ (((L >> 7) & 7) << 4);
            gload16(Kb + (size_t)(kv0 + (a >> 7)) * (DH * 2) + (a & 127), Ksm + r * 4096 + w * 1024);
        }
        // stage V transposed: element (t,d) -> Vsm byte d*128 + (t*2 ^ (vm(d)<<4))
#pragma unroll
        for (int r = 0; r < 2; ++r) {
            int idx = r * 2048 + tid * 8;
            int trow = idx >> 6;
            int d0 = idx & 63;
            short8 vv = *(const short8*)(Vb + (size_t)(kv0 + trow) * (DH * 2) + d0 * 2);
#pragma unroll
            for (int j = 0; j < 8; ++j) {
                int d = d0 + j;
                int vm = (d ^ (d >> 3)) & 7;
                *(unsigned short*)(Vsm + d * 128 + ((trow * 2) ^ (vm << 4))) = (unsigned short)vv[j];
            }
        }
        __syncthreads();

        // ---- S = Q K^T ----
        f32x4 sc[2][4] = {};
#pragma unroll
        for (int ks = 0; ks < 2; ++ks) {
            short8 kf[4];
#pragma unroll
            for (int nf = 0; nf < 4; ++nf) {
                int trow = nf * 16 + (lane & 15);
                int a = trow * 128 + ks * 64 + ((lane >> 4) << 4);
                kf[nf] = *(const short8*)(Ksm + (a ^ ((trow & 7) << 4)));
            }
#pragma unroll
            for (int mf = 0; mf < 2; ++mf)
#pragma unroll
                for (int nf = 0; nf < 4; ++nf)
                    sc[mf][nf] = __builtin_amdgcn_mfma_f32_16x16x32_bf16(qf[mf][ks], kf[nf], sc[mf][nf], 0, 0, 0);
        }

        // scale, then mask (reference order: scores/sqrt(dk), then where(mask==0, -1e9))
#pragma unroll
        for (int mf = 0; mf < 2; ++mf)
#pragma unroll
            for (int nf = 0; nf < 4; ++nf)
#pragma unroll
                for (int i = 0; i < 4; ++i) sc[mf][nf][i] *= 0.125f;
        if (!allones) {
#pragma unroll
            for (int mf = 0; mf < 2; ++mf)
#pragma unroll
                for (int i = 0; i < 4; ++i) {
                    int row = q0 + w * 32 + mf * 16 + ((lane >> 4) << 2) + i;
#pragma unroll
                    for (int nf = 0; nf < 4; ++nf) {
                        int t = kv0 + nf * 16 + (lane & 15);
                        if (!((mbits[row * (S_LEN / 32) + (t >> 5)] >> (t & 31)) & 1u))
                            sc[mf][nf][i] = -1e9f;
                    }
                }
        }

        // ---- online softmax (rows live on 16-lane groups) ----
#pragma unroll
        for (int mf = 0; mf < 2; ++mf)
#pragma unroll
            for (int i = 0; i < 4; ++i) {
                float pm = fmaxf(fmaxf(sc[mf][0][i], sc[mf][1][i]), fmaxf(sc[mf][2][i], sc[mf][3][i]));
                pm = fmaxf(pm, __shfl_xor(pm, 1));
                pm = fmaxf(pm, __shfl_xor(pm, 2));
                pm = fmaxf(pm, __shfl_xor(pm, 4));
                pm = fmaxf(pm, __shfl_xor(pm, 8));
                float mnew = fmaxf(mstate[mf][i], pm);
                float corr = exp2f((mstate[mf][i] - mnew) * LOG2E);
                float rs = 0.f;
#pragma unroll
                for (int nf = 0; nf < 4; ++nf) {
                    float p = exp2f((sc[mf][nf][i] - mnew) * LOG2E);
                    sc[mf][nf][i] = p;
                    rs += p;
                }
                rs += __shfl_xor(rs, 1);
                rs += __shfl_xor(rs, 2);
                rs += __shfl_xor(rs, 4);
                rs += __shfl_xor(rs, 8);
                lstate[mf][i] = lstate[mf][i] * corr + rs;
                mstate[mf][i] = mnew;
#pragma unroll
                for (int nfo = 0; nfo < 4; ++nfo) o[mf][nfo][i] *= corr;
            }

        // ---- P -> per-wave LDS (bf16, swizzled) ----
#pragma unroll
        for (int mf = 0; mf < 2; ++mf)
#pragma unroll
            for (int nf = 0; nf < 4; ++nf)
#pragma unroll
                for (int i = 0; i < 4; ++i) {
                    int prow = mf * 16 + ((lane >> 4) << 2) + i;
                    int a = prow * 128 + (nf * 16 + (lane & 15)) * 2;
                    *(unsigned short*)(Pw + (a ^ ((prow & 7) << 4))) = f2bf(sc[mf][nf][i]);
                }

        // ---- O += P V ----
#pragma unroll
        for (int ks = 0; ks < 2; ++ks) {
            short8 pa[2], vf[4];
#pragma unroll
            for (int mf = 0; mf < 2; ++mf) {
                int prow = mf * 16 + (lane & 15);
                int a = prow * 128 + ks * 64 + ((lane >> 4) << 4);
                pa[mf] = *(const short8*)(Pw + (a ^ ((prow & 7) << 4)));
            }
#pragma unroll
            for (int nfo = 0; nfo < 4; ++nfo) {
                int d = nfo * 16 + (lane & 15);
                int vm = (d ^ (d >> 3)) & 7;
                int tb = (ks * 64 + ((lane >> 4) << 4)) ^ (vm << 4);
                vf[nfo] = *(const short8*)(Vsm + d * 128 + tb);
            }
#pragma unroll
            for (int mf = 0; mf < 2; ++mf)
#pragma unroll
                for (int nfo = 0; nfo < 4; ++nfo)
                    o[mf][nfo] = __builtin_amdgcn_mfma_f32_16x16x32_bf16(pa[mf], vf[nfo], o[mf][nfo], 0, 0, 0);
        }
    }

    // ---- epilogue: normalize, write ctx as [B][S][H*64] row-major (= GEMM A) ----
    const int b = bh >> 4;
    const int h = bh & 15;
#pragma unroll
    for (int mf = 0; mf < 2; ++mf)
#pragma unroll
        for (int nfo = 0; nfo < 4; ++nfo)
#pragma unroll
            for (int i = 0; i < 4; ++i) {
                int srow = q0 + w * 32 + mf * 16 + ((lane >> 4) << 2) + i;
                int e = nfo * 16 + (lane & 15);
                float val = o[mf][nfo][i] / lstate[mf][i];
                ctx[((size_t)(b * S_LEN + srow)) * DM + h * DH + e] = f2bf(val);
            }
}

// ---------------- launcher ----------------
extern "C" void kernel_launch(void* const* d_in, const int* in_sizes, int n_in,
                              void* d_out, int out_size, void* d_ws, size_t ws_size,
                              hipStream_t stream)
{
    const float* q    = (const float*)d_in[0];
    const float* k    = (const float*)d_in[1];
    const float* v    = (const float*)d_in[2];
    const int*   mask = (const int*)d_in[3];
    const float* Wq   = (const float*)d_in[4];
    const float* bq   = (const float*)d_in[5];
    const float* Wk   = (const float*)d_in[6];
    const float* bk   = (const float*)d_in[7];
    const float* Wv   = (const float*)d_in[8];
    const float* bv   = (const float*)d_in[9];
    const float* Wo   = (const float*)d_in[10];

    // workspace layout (ctx aliases qkvb: qkvb dead after gemm<0>, ctx written by attn)
    char* W = (char*)d_ws;
    unsigned short* qkvb = (unsigned short*)(W + 0);           // 3 x 4194304 bf16 (25165824 B)
    unsigned short* ctx  = (unsigned short*)(W + 0);           // 4194304 bf16 (8388608 B), aliases qkvb
    unsigned short* Wt   = (unsigned short*)(W + 25165824);    // 3 x 1048576 bf16 (6291456 B)
    unsigned short* QKVh = (unsigned short*)(W + 31457280);    // 3 x 4194304 bf16 (25165824 B)
    unsigned short* Wot  = (unsigned short*)(W + 56623104);    // 1048576 bf16 (2097152 B)
    unsigned int*   mbits= (unsigned int*)(W + 58720256);      // 524288 B
    int*            flag = (int*)(W + 59244544);               // 4 B
    if (ws_size < (size_t)59244548) return;                    // ws too small -> visible failure

    initflag_kernel<<<1, 64, 0, stream>>>(flag);
    convert3<<<4096, 256, 0, stream>>>(q, k, v, qkvb, qkvb + 4194304, qkvb + 8388608, 1048576);
    transpose_bf16<<<dim3(32, 2, 16), 256, 0, stream>>>(Wq, Wt,            1024, 64);
    transpose_bf16<<<dim3(32, 2, 16), 256, 0, stream>>>(Wk, Wt + 1048576,  1024, 64);
    transpose_bf16<<<dim3(32, 2, 16), 256, 0, stream>>>(Wv, Wt + 2097152,  1024, 64);
    transpose_bf16<<<dim3(32, 32, 1), 256, 0, stream>>>(Wo, Wot,           1024, 1024);
    maskbits_kernel<<<512, 256, 0, stream>>>(mask, mbits, flag);
    gemm128<0><<<dim3(8, 32, 3), 256, 0, stream>>>(qkvb, Wt, bq, bk, bv, (void*)QKVh);
    attn_kernel<<<dim3(16, 32), 256, 0, stream>>>(QKVh, QKVh + 4194304, QKVh + 8388608, ctx, mbits, flag);
    gemm128<1><<<dim3(8, 32, 1), 256, 0, stream>>>(ctx, Wot, nullptr, nullptr, nullptr, d_out);
}

// Round 8
// 349.854 us; speedup vs baseline: 1.2096x; 1.2096x over previous
//
#include <hip/hip_runtime.h>
#include <math.h>

// ---------------- constants for this problem ----------------
#define S_LEN 2048
#define DM    1024
#define NH    16
#define DH    64
#define BATCH 2
#define MROWS 4096        // BATCH * S_LEN
#define LOG2E 1.44269504088896340736f

typedef __attribute__((ext_vector_type(8))) short short8;   // 8 x bf16 (4 VGPRs)
typedef __attribute__((ext_vector_type(4))) float f32x4;

// fp32 -> bf16 round-to-nearest-even (finite inputs)
__device__ __forceinline__ unsigned short f2bf(float f) {
    unsigned int u = __float_as_uint(f);
    u += 0x7FFFu + ((u >> 16) & 1u);
    return (unsigned short)(u >> 16);
}

// async global->LDS, 16B per lane; LDS dest = wave-uniform base + lane*16
__device__ __forceinline__ void gload16(const void* g, void* lds) {
    __builtin_amdgcn_global_load_lds((const __attribute__((address_space(1))) void*)g,
                                     (__attribute__((address_space(3))) void*)lds,
                                     16, 0, 0);
}

// ---------------- small prep kernels ----------------
__global__ void initflag_kernel(int* flag) {
    if (threadIdx.x == 0 && blockIdx.x == 0) *flag = 1;
}

__global__ __launch_bounds__(256) void convert3(
    const float* __restrict__ q, const float* __restrict__ k, const float* __restrict__ v,
    unsigned short* __restrict__ qb, unsigned short* __restrict__ kb, unsigned short* __restrict__ vb,
    int n4)
{
    int i = blockIdx.x * 256 + threadIdx.x;
    if (i >= n4) return;
    float4 a = ((const float4*)q)[i];
    float4 b = ((const float4*)k)[i];
    float4 c = ((const float4*)v)[i];
    ((ushort4*)qb)[i] = make_ushort4(f2bf(a.x), f2bf(a.y), f2bf(a.z), f2bf(a.w));
    ((ushort4*)kb)[i] = make_ushort4(f2bf(b.x), f2bf(b.y), f2bf(b.z), f2bf(b.w));
    ((ushort4*)vb)[i] = make_ushort4(f2bf(c.x), f2bf(c.y), f2bf(c.z), f2bf(c.w));
}

// transpose [R][C] fp32 slab -> [C][R] bf16 slab (slab = blockIdx.z * R * C for both)
__global__ __launch_bounds__(256) void transpose_bf16(
    const float* __restrict__ in, unsigned short* __restrict__ out, int R, int C)
{
    __shared__ float tile[32][33];
    const size_t slab = (size_t)blockIdx.z * R * C;
    const int r0 = blockIdx.x * 32;
    const int c0 = blockIdx.y * 32;
    const int tr = threadIdx.x >> 5;
    const int tc = threadIdx.x & 31;
#pragma unroll
    for (int j = 0; j < 32; j += 8)
        tile[tr + j][tc] = in[slab + (size_t)(r0 + tr + j) * C + c0 + tc];
    __syncthreads();
#pragma unroll
    for (int j = 0; j < 32; j += 8)
        out[slab + (size_t)(c0 + tr + j) * R + r0 + tc] = f2bf(tile[tc][tr + j]);
}

// mask[S*S] int32 -> bit per element; flag &= all-ones
__global__ __launch_bounds__(256) void maskbits_kernel(
    const int* __restrict__ mask, unsigned int* __restrict__ bits, int* __restrict__ flag)
{
    int widx = blockIdx.x * 256 + threadIdx.x;      // word index, 131072 total
    const int4* src = (const int4*)(mask + (size_t)widx * 32);
    unsigned int wb = 0;
#pragma unroll
    for (int j = 0; j < 8; ++j) {
        int4 vv = src[j];
        wb |= (vv.x != 0 ? 1u : 0u) << (4 * j);
        wb |= (vv.y != 0 ? 1u : 0u) << (4 * j + 1);
        wb |= (vv.z != 0 ? 1u : 0u) << (4 * j + 2);
        wb |= (vv.w != 0 ? 1u : 0u) << (4 * j + 3);
    }
    bits[widx] = wb;
    if (wb != 0xFFFFFFFFu) atomicAnd(flag, 0);
}

// ---------------- 128x128 bf16 GEMM (K=1024 fixed), m97-style ----------------
// (unchanged — validated round 6; revisit once attn fix surfaces its counters)
template<int MODE>
__global__ __launch_bounds__(256) void gemm128(
    const unsigned short* __restrict__ Aall,
    const unsigned short* __restrict__ Btall,
    const float* __restrict__ bias0, const float* __restrict__ bias1, const float* __restrict__ bias2,
    void* __restrict__ outp)
{
    __shared__ __attribute__((aligned(16))) unsigned short Asm[128 * 64];
    __shared__ __attribute__((aligned(16))) unsigned short Bsm[128 * 64];
    char* AsmC = (char*)Asm;
    char* BsmC = (char*)Bsm;
    const int tid  = threadIdx.x;
    const int w    = tid >> 6;
    const int lane = tid & 63;
    const int m0 = blockIdx.y * 128;
    const int n0 = blockIdx.x * 128;
    const int z  = blockIdx.z;

    const char* Ac = (const char*)(Aall + (size_t)z * MROWS * DM);
    const char* Bc = (const char*)(Btall + (size_t)z * DM * DM);

    int arow[4], akof[4];
#pragma unroll
    for (int r = 0; r < 4; ++r) {
        int L = r * 4096 + tid * 16;
        int a = L ^ (((L >> 7) & 7) << 4);
        arow[r] = a >> 7;
        akof[r] = a & 127;
    }

    const int wr = (w >> 1) * 64;
    const int wc = (w & 1) * 64;
    int aaddr[4], baddr[4];
#pragma unroll
    for (int f = 0; f < 4; ++f) {
        int rr = wr + f * 16 + (lane & 15);
        aaddr[f] = (rr * 128 + ((lane >> 4) << 4)) ^ ((rr & 7) << 4);
        int rn = wc + f * 16 + (lane & 15);
        baddr[f] = (rn * 128 + ((lane >> 4) << 4)) ^ ((rn & 7) << 4);
    }

    f32x4 acc[4][4] = {};

    for (int kt = 0; kt < 16; ++kt) {
        __syncthreads();
#pragma unroll
        for (int r = 0; r < 4; ++r) {
            gload16(Ac + (size_t)(m0 + arow[r]) * (DM * 2) + kt * 128 + akof[r],
                    AsmC + r * 4096 + w * 1024);
            gload16(Bc + (size_t)(n0 + arow[r]) * (DM * 2) + kt * 128 + akof[r],
                    BsmC + r * 4096 + w * 1024);
        }
        __syncthreads();
#pragma unroll
        for (int ks = 0; ks < 2; ++ks) {
            short8 af[4], bf[4];
#pragma unroll
            for (int f = 0; f < 4; ++f) af[f] = *(const short8*)(AsmC + (aaddr[f] ^ (ks << 6)));
#pragma unroll
            for (int f = 0; f < 4; ++f) bf[f] = *(const short8*)(BsmC + (baddr[f] ^ (ks << 6)));
#pragma unroll
            for (int mf = 0; mf < 4; ++mf)
#pragma unroll
                for (int nf = 0; nf < 4; ++nf)
                    acc[mf][nf] = __builtin_amdgcn_mfma_f32_16x16x32_bf16(af[mf], bf[nf], acc[mf][nf], 0, 0, 0);
        }
    }

    if constexpr (MODE == 0) {
        const float* bias = (z == 0) ? bias0 : (z == 1) ? bias1 : bias2;
        unsigned short* out = ((unsigned short*)outp) + (size_t)z * MROWS * DM;
        float bv[4];
#pragma unroll
        for (int nf = 0; nf < 4; ++nf) bv[nf] = bias[n0 + wc + nf * 16 + (lane & 15)];
#pragma unroll
        for (int mf = 0; mf < 4; ++mf)
#pragma unroll
            for (int nf = 0; nf < 4; ++nf)
#pragma unroll
                for (int i = 0; i < 4; ++i) {
                    int grow = m0 + wr + mf * 16 + ((lane >> 4) << 2) + i;
                    int gcol = n0 + wc + nf * 16 + (lane & 15);
                    float val = acc[mf][nf][i] + bv[nf];
                    int b = grow >> 11, srow = grow & 2047, h = gcol >> 6, e = gcol & 63;
                    out[((size_t)(b * NH + h) * S_LEN + srow) * DH + e] = f2bf(val);
                }
    } else {
        float* out = (float*)outp;
#pragma unroll
        for (int mf = 0; mf < 4; ++mf)
#pragma unroll
            for (int nf = 0; nf < 4; ++nf)
#pragma unroll
                for (int i = 0; i < 4; ++i) {
                    int grow = m0 + wr + mf * 16 + ((lane >> 4) << 2) + i;
                    int gcol = n0 + wc + nf * 16 + (lane & 15);
                    out[(size_t)grow * DM + gcol] = acc[mf][nf][i];
                }
    }
}

// ---------------- flash attention, v2 ----------------
// grid (32 q-tiles, 32 bh) = 1024 blocks -> 4 blocks/CU.  QBLK=64: 4 waves x 16 q-rows.
// 2-phase double-buffered K/V: stage(kv+1) issued before compute(kv); ONE barrier/iter.
// K via gload_lds (pre-unswizzled source). V via reg-staged t-pair packing:
// (t,d) stored as u32 {t even lo, t odd hi} at Vsm + d*128 + ((t>>1)*4 ^ (vm(d)<<4)),
// vm(d) = (d^(d>>3))&7 -> b32 writes ~2-way, PV reads one b128 per fragment.
// P per-wave 16x64 bf16 at swizzle ((r^(r>>2))&7)<<4 -> 2-way both sides.
__global__ __launch_bounds__(256, 4) void attn_kernel(
    const unsigned short* __restrict__ Qh, const unsigned short* __restrict__ Kh,
    const unsigned short* __restrict__ Vh, unsigned short* __restrict__ ctx,
    const unsigned int* __restrict__ mbits, const int* __restrict__ flag)
{
    __shared__ __attribute__((aligned(16))) char smem[16384 + 16384 + 8192];
    char* KsmB = smem;            // 2 x 8KB
    char* VsmB = smem + 16384;    // 2 x 8KB
    char* QP   = smem + 32768;    // 8KB: Q stage, then per-wave P (wave w owns [w*2048, +2048))

    const int tid  = threadIdx.x;
    const int w    = tid >> 6;
    const int lane = tid & 63;
    const int q0 = blockIdx.x * 64;
    const int bh = blockIdx.y;

    const char* Qb = (const char*)(Qh + (size_t)bh * S_LEN * DH);
    const char* Kb = (const char*)(Kh + (size_t)bh * S_LEN * DH);
    const char* Vb = (const char*)(Vh + (size_t)bh * S_LEN * DH);

    // ---- stage Q tile (64 x 64 bf16 = 8KB), swizzled; hoist fragments ----
#pragma unroll
    for (int r = 0; r < 2; ++r) {
        int L = r * 4096 + tid * 16;
        int a = L ^ (((L >> 7) & 7) << 4);
        gload16(Qb + (size_t)(q0 + (a >> 7)) * 128 + (a & 127), QP + r * 4096 + w * 1024);
    }
    __syncthreads();
    short8 qf[2];
#pragma unroll
    for (int ks = 0; ks < 2; ++ks) {
        int row = w * 16 + (lane & 15);
        int a = row * 128 + ks * 64 + ((lane >> 4) << 4);
        qf[ks] = *(const short8*)(QP + (a ^ ((row & 7) << 4)));
    }
    __syncthreads();   // Q fully consumed before P reuses the region

    const bool allones = (*flag) != 0;

    float mstate[4], lstate[4];
#pragma unroll
    for (int i = 0; i < 4; ++i) { mstate[i] = -INFINITY; lstate[i] = 0.f; }
    f32x4 o[4] = {};

    char* Pw = QP + w * 2048;

    // V reg-staging state (t-pair loads held across compute)
    const int vp = tid >> 4;            // pair-slot 0..15
    const int vd0 = (tid & 15) * 4;     // d quad base
    uint2 va[2], vb2[2];

    // ---- prologue: stage kv=0 into buffer 0 ----
#pragma unroll
    for (int r = 0; r < 2; ++r) {
        int L = r * 4096 + tid * 16;
        int a = L ^ (((L >> 7) & 7) << 4);
        gload16(Kb + (size_t)(a >> 7) * 128 + (a & 127), KsmB + r * 4096 + w * 1024);
    }
#pragma unroll
    for (int r = 0; r < 2; ++r) {
        int t0 = (r * 16 + vp) * 2;
        va[r]  = *(const uint2*)(Vb + (size_t)t0 * 128 + vd0 * 2);
        vb2[r] = *(const uint2*)(Vb + (size_t)(t0 + 1) * 128 + vd0 * 2);
    }
#pragma unroll
    for (int r = 0; r < 2; ++r) {
        int pp = r * 16 + vp;
        int d = vd0;
        int vm0 = (d ^ (d >> 3)) & 7;       int vm1 = ((d+1) ^ ((d+1) >> 3)) & 7;
        int vm2 = ((d+2) ^ ((d+2) >> 3)) & 7; int vm3 = ((d+3) ^ ((d+3) >> 3)) & 7;
        *(unsigned int*)(VsmB + (d+0) * 128 + ((pp * 4) ^ (vm0 << 4))) = (va[r].x & 0xffffu) | (vb2[r].x << 16);
        *(unsigned int*)(VsmB + (d+1) * 128 + ((pp * 4) ^ (vm1 << 4))) = (va[r].x >> 16)     | (vb2[r].x & 0xffff0000u);
        *(unsigned int*)(VsmB + (d+2) * 128 + ((pp * 4) ^ (vm2 << 4))) = (va[r].y & 0xffffu) | (vb2[r].y << 16);
        *(unsigned int*)(VsmB + (d+3) * 128 + ((pp * 4) ^ (vm3 << 4))) = (va[r].y >> 16)     | (vb2[r].y & 0xffff0000u);
    }
    __syncthreads();

    for (int kv = 0; kv < 32; ++kv) {
        char* Kc = KsmB + (kv & 1) * 8192;
        char* Vc = VsmB + (kv & 1) * 8192;
        char* Kn = KsmB + ((kv & 1) ^ 1) * 8192;
        char* Vn = VsmB + ((kv & 1) ^ 1) * 8192;
        const bool more = (kv + 1 < 32);
        const int kv0 = kv * 64;

        // ---- issue next tile's loads (hidden under this tile's compute) ----
        if (more) {
            const int kv1 = kv0 + 64;
#pragma unroll
            for (int r = 0; r < 2; ++r) {
                int L = r * 4096 + tid * 16;
                int a = L ^ (((L >> 7) & 7) << 4);
                gload16(Kb + (size_t)(kv1 + (a >> 7)) * 128 + (a & 127), Kn + r * 4096 + w * 1024);
            }
#pragma unroll
            for (int r = 0; r < 2; ++r) {
                int t0 = kv1 + (r * 16 + vp) * 2;
                va[r]  = *(const uint2*)(Vb + (size_t)t0 * 128 + vd0 * 2);
                vb2[r] = *(const uint2*)(Vb + (size_t)(t0 + 1) * 128 + vd0 * 2);
            }
        }

        // ---- S = Q K^T ----
        f32x4 sc[4] = {};
#pragma unroll
        for (int ks = 0; ks < 2; ++ks) {
            short8 kf[4];
#pragma unroll
            for (int nf = 0; nf < 4; ++nf) {
                int trow = nf * 16 + (lane & 15);
                int a = trow * 128 + ks * 64 + ((lane >> 4) << 4);
                kf[nf] = *(const short8*)(Kc + (a ^ ((trow & 7) << 4)));
            }
#pragma unroll
            for (int nf = 0; nf < 4; ++nf)
                sc[nf] = __builtin_amdgcn_mfma_f32_16x16x32_bf16(qf[ks], kf[nf], sc[nf], 0, 0, 0);
        }

        // scale, then mask (reference order)
#pragma unroll
        for (int nf = 0; nf < 4; ++nf)
#pragma unroll
            for (int i = 0; i < 4; ++i) sc[nf][i] *= 0.125f;
        if (!allones) {
#pragma unroll
            for (int i = 0; i < 4; ++i) {
                int row = q0 + w * 16 + ((lane >> 4) << 2) + i;
#pragma unroll
                for (int nf = 0; nf < 4; ++nf) {
                    int t = kv0 + nf * 16 + (lane & 15);
                    if (!((mbits[row * (S_LEN / 32) + (t >> 5)] >> (t & 31)) & 1u))
                        sc[nf][i] = -1e9f;
                }
            }
        }

        // ---- online softmax (rows on 16-lane groups) ----
#pragma unroll
        for (int i = 0; i < 4; ++i) {
            float pm = fmaxf(fmaxf(sc[0][i], sc[1][i]), fmaxf(sc[2][i], sc[3][i]));
            pm = fmaxf(pm, __shfl_xor(pm, 1));
            pm = fmaxf(pm, __shfl_xor(pm, 2));
            pm = fmaxf(pm, __shfl_xor(pm, 4));
            pm = fmaxf(pm, __shfl_xor(pm, 8));
            float mnew = fmaxf(mstate[i], pm);
            float corr = exp2f((mstate[i] - mnew) * LOG2E);
            float rs = 0.f;
#pragma unroll
            for (int nf = 0; nf < 4; ++nf) {
                float p = exp2f((sc[nf][i] - mnew) * LOG2E);
                sc[nf][i] = p;
                rs += p;
            }
            rs += __shfl_xor(rs, 1);
            rs += __shfl_xor(rs, 2);
            rs += __shfl_xor(rs, 4);
            rs += __shfl_xor(rs, 8);
            lstate[i] = lstate[i] * corr + rs;
            mstate[i] = mnew;
#pragma unroll
            for (int nfo = 0; nfo < 4; ++nfo) o[nfo][i] *= corr;
        }

        // ---- P -> per-wave LDS (bf16, swizzle ((r^(r>>2))&7)<<4) ----
#pragma unroll
        for (int nf = 0; nf < 4; ++nf)
#pragma unroll
            for (int i = 0; i < 4; ++i) {
                int prow = ((lane >> 4) << 2) + i;
                int a = prow * 128 + (nf * 16 + (lane & 15)) * 2;
                *(unsigned short*)(Pw + (a ^ (((prow ^ (prow >> 2)) & 7) << 4))) = f2bf(sc[nf][i]);
            }

        // ---- O += P V ----
#pragma unroll
        for (int ks = 0; ks < 2; ++ks) {
            int prow = lane & 15;
            int ap = prow * 128 + ks * 64 + ((lane >> 4) << 4);
            short8 pa = *(const short8*)(Pw + (ap ^ (((prow ^ (prow >> 2)) & 7) << 4)));
#pragma unroll
            for (int nfo = 0; nfo < 4; ++nfo) {
                int d = nfo * 16 + (lane & 15);
                int vm = (d ^ (d >> 3)) & 7;
                int p0 = ks * 16 + ((lane >> 4) << 2);
                short8 vf = *(const short8*)(Vc + d * 128 + ((p0 * 4) ^ (vm << 4)));
                o[nfo] = __builtin_amdgcn_mfma_f32_16x16x32_bf16(pa, vf, o[nfo], 0, 0, 0);
            }
        }

        // ---- write next V tile into LDS (loads have had a full compute to land) ----
        if (more) {
#pragma unroll
            for (int r = 0; r < 2; ++r) {
                int pp = r * 16 + vp;
                int d = vd0;
                int vm0 = (d ^ (d >> 3)) & 7;       int vm1 = ((d+1) ^ ((d+1) >> 3)) & 7;
                int vm2 = ((d+2) ^ ((d+2) >> 3)) & 7; int vm3 = ((d+3) ^ ((d+3) >> 3)) & 7;
                *(unsigned int*)(Vn + (d+0) * 128 + ((pp * 4) ^ (vm0 << 4))) = (va[r].x & 0xffffu) | (vb2[r].x << 16);
                *(unsigned int*)(Vn + (d+1) * 128 + ((pp * 4) ^ (vm1 << 4))) = (va[r].x >> 16)     | (vb2[r].x & 0xffff0000u);
                *(unsigned int*)(Vn + (d+2) * 128 + ((pp * 4) ^ (vm2 << 4))) = (va[r].y & 0xffffu) | (vb2[r].y << 16);
                *(unsigned int*)(Vn + (d+3) * 128 + ((pp * 4) ^ (vm3 << 4))) = (va[r].y >> 16)     | (vb2[r].y & 0xffff0000u);
            }
        }
        __syncthreads();
    }

    // ---- epilogue ----
    const int b = bh >> 4;
    const int h = bh & 15;
#pragma unroll
    for (int nfo = 0; nfo < 4; ++nfo)
#pragma unroll
        for (int i = 0; i < 4; ++i) {
            int srow = q0 + w * 16 + ((lane >> 4) << 2) + i;
            int e = nfo * 16 + (lane & 15);
            float val = o[nfo][i] / lstate[i];
            ctx[((size_t)(b * S_LEN + srow)) * DM + h * DH + e] = f2bf(val);
        }
}

// ---------------- launcher ----------------
extern "C" void kernel_launch(void* const* d_in, const int* in_sizes, int n_in,
                              void* d_out, int out_size, void* d_ws, size_t ws_size,
                              hipStream_t stream)
{
    const float* q    = (const float*)d_in[0];
    const float* k    = (const float*)d_in[1];
    const float* v    = (const float*)d_in[2];
    const int*   mask = (const int*)d_in[3];
    const float* Wq   = (const float*)d_in[4];
    const float* bq   = (const float*)d_in[5];
    const float* Wk   = (const float*)d_in[6];
    const float* bk   = (const float*)d_in[7];
    const float* Wv   = (const float*)d_in[8];
    const float* bv   = (const float*)d_in[9];
    const float* Wo   = (const float*)d_in[10];

    // workspace layout (ctx aliases qkvb: qkvb dead after gemm<0>, ctx written by attn)
    char* W = (char*)d_ws;
    unsigned short* qkvb = (unsigned short*)(W + 0);           // 3 x 4194304 bf16 (25165824 B)
    unsigned short* ctx  = (unsigned short*)(W + 0);           // 4194304 bf16, aliases qkvb
    unsigned short* Wt   = (unsigned short*)(W + 25165824);    // 3 x 1048576 bf16 (6291456 B)
    unsigned short* QKVh = (unsigned short*)(W + 31457280);    // 3 x 4194304 bf16 (25165824 B)
    unsigned short* Wot  = (unsigned short*)(W + 56623104);    // 1048576 bf16 (2097152 B)
    unsigned int*   mbits= (unsigned int*)(W + 58720256);      // 524288 B
    int*            flag = (int*)(W + 59244544);               // 4 B
    if (ws_size < (size_t)59244548) return;                    // ws too small -> visible failure

    initflag_kernel<<<1, 64, 0, stream>>>(flag);
    convert3<<<4096, 256, 0, stream>>>(q, k, v, qkvb, qkvb + 4194304, qkvb + 8388608, 1048576);
    transpose_bf16<<<dim3(32, 2, 16), 256, 0, stream>>>(Wq, Wt,            1024, 64);
    transpose_bf16<<<dim3(32, 2, 16), 256, 0, stream>>>(Wk, Wt + 1048576,  1024, 64);
    transpose_bf16<<<dim3(32, 2, 16), 256, 0, stream>>>(Wv, Wt + 2097152,  1024, 64);
    transpose_bf16<<<dim3(32, 32, 1), 256, 0, stream>>>(Wo, Wot,           1024, 1024);
    maskbits_kernel<<<512, 256, 0, stream>>>(mask, mbits, flag);
    gemm128<0><<<dim3(8, 32, 3), 256, 0, stream>>>(qkvb, Wt, bq, bk, bv, (void*)QKVh);
    attn_kernel<<<dim3(32, 32), 256, 0, stream>>>(QKVh, QKVh + 4194304, QKVh + 8388608, ctx, mbits, flag);
    gemm128<1><<<dim3(8, 32, 1), 256, 0, stream>>>(ctx, Wot, nullptr, nullptr, nullptr, d_out);
}

// Round 9
// 299.597 us; speedup vs baseline: 1.4125x; 1.1677x over previous
//
#include <hip/hip_runtime.h>
#include <math.h>

// ---------------- constants for this problem ----------------
#define S_LEN 2048
#define DM    1024
#define NH    16
#define DH    64
#define BATCH 2
#define MROWS 4096        // BATCH * S_LEN
#define LOG2E 1.44269504088896340736f

typedef __attribute__((ext_vector_type(8))) short short8;   // 8 x bf16 (4 VGPRs)
typedef __attribute__((ext_vector_type(4))) float f32x4;

// fp32 -> bf16 round-to-nearest-even (finite inputs)
__device__ __forceinline__ unsigned short f2bf(float f) {
    unsigned int u = __float_as_uint(f);
    u += 0x7FFFu + ((u >> 16) & 1u);
    return (unsigned short)(u >> 16);
}

// async global->LDS, 16B per lane; LDS dest = wave-uniform base + lane*16
__device__ __forceinline__ void gload16(const void* g, void* lds) {
    __builtin_amdgcn_global_load_lds((const __attribute__((address_space(1))) void*)g,
                                     (__attribute__((address_space(3))) void*)lds,
                                     16, 0, 0);
}

// ---------------- small prep kernels ----------------
__global__ void initflag_kernel(int* flag) {
    if (threadIdx.x == 0 && blockIdx.x == 0) *flag = 1;
}

__global__ __launch_bounds__(256) void convert3(
    const float* __restrict__ q, const float* __restrict__ k, const float* __restrict__ v,
    unsigned short* __restrict__ qb, unsigned short* __restrict__ kb, unsigned short* __restrict__ vb,
    int n4)
{
    int i = blockIdx.x * 256 + threadIdx.x;
    if (i >= n4) return;
    float4 a = ((const float4*)q)[i];
    float4 b = ((const float4*)k)[i];
    float4 c = ((const float4*)v)[i];
    ((ushort4*)qb)[i] = make_ushort4(f2bf(a.x), f2bf(a.y), f2bf(a.z), f2bf(a.w));
    ((ushort4*)kb)[i] = make_ushort4(f2bf(b.x), f2bf(b.y), f2bf(b.z), f2bf(b.w));
    ((ushort4*)vb)[i] = make_ushort4(f2bf(c.x), f2bf(c.y), f2bf(c.z), f2bf(c.w));
}

// transpose [R][C] fp32 slab -> [C][R] bf16 slab (slab = blockIdx.z * R * C for both)
__global__ __launch_bounds__(256) void transpose_bf16(
    const float* __restrict__ in, unsigned short* __restrict__ out, int R, int C)
{
    __shared__ float tile[32][33];
    const size_t slab = (size_t)blockIdx.z * R * C;
    const int r0 = blockIdx.x * 32;
    const int c0 = blockIdx.y * 32;
    const int tr = threadIdx.x >> 5;
    const int tc = threadIdx.x & 31;
#pragma unroll
    for (int j = 0; j < 32; j += 8)
        tile[tr + j][tc] = in[slab + (size_t)(r0 + tr + j) * C + c0 + tc];
    __syncthreads();
#pragma unroll
    for (int j = 0; j < 32; j += 8)
        out[slab + (size_t)(c0 + tr + j) * R + r0 + tc] = f2bf(tile[tc][tr + j]);
}

// mask[S*S] int32 -> bit per element; flag &= all-ones
__global__ __launch_bounds__(256) void maskbits_kernel(
    const int* __restrict__ mask, unsigned int* __restrict__ bits, int* __restrict__ flag)
{
    int widx = blockIdx.x * 256 + threadIdx.x;      // word index, 131072 total
    const int4* src = (const int4*)(mask + (size_t)widx * 32);
    unsigned int wb = 0;
#pragma unroll
    for (int j = 0; j < 8; ++j) {
        int4 vv = src[j];
        wb |= (vv.x != 0 ? 1u : 0u) << (4 * j);
        wb |= (vv.y != 0 ? 1u : 0u) << (4 * j + 1);
        wb |= (vv.z != 0 ? 1u : 0u) << (4 * j + 2);
        wb |= (vv.w != 0 ? 1u : 0u) << (4 * j + 3);
    }
    bits[widx] = wb;
    if (wb != 0xFFFFFFFFu) atomicAnd(flag, 0);
}

// ---------------- 128x128 bf16 GEMM (K=1024 fixed), m97-style ----------------
// MODE 0: out = bf16, (acc+bias)*0.125 for z==0 (attn scale folded into Q), scattered
//         to [B][H][S][64] head-major.  MODE 1: out = fp32 row-major (d_out).
template<int MODE>
__global__ __launch_bounds__(256) void gemm128(
    const unsigned short* __restrict__ Aall,
    const unsigned short* __restrict__ Btall,
    const float* __restrict__ bias0, const float* __restrict__ bias1, const float* __restrict__ bias2,
    void* __restrict__ outp)
{
    __shared__ __attribute__((aligned(16))) unsigned short Asm[128 * 64];
    __shared__ __attribute__((aligned(16))) unsigned short Bsm[128 * 64];
    char* AsmC = (char*)Asm;
    char* BsmC = (char*)Bsm;
    const int tid  = threadIdx.x;
    const int w    = tid >> 6;
    const int lane = tid & 63;
    const int m0 = blockIdx.y * 128;
    const int n0 = blockIdx.x * 128;
    const int z  = blockIdx.z;

    const char* Ac = (const char*)(Aall + (size_t)z * MROWS * DM);
    const char* Bc = (const char*)(Btall + (size_t)z * DM * DM);

    int arow[4], akof[4];
#pragma unroll
    for (int r = 0; r < 4; ++r) {
        int L = r * 4096 + tid * 16;
        int a = L ^ (((L >> 7) & 7) << 4);
        arow[r] = a >> 7;
        akof[r] = a & 127;
    }

    const int wr = (w >> 1) * 64;
    const int wc = (w & 1) * 64;
    int aaddr[4], baddr[4];
#pragma unroll
    for (int f = 0; f < 4; ++f) {
        int rr = wr + f * 16 + (lane & 15);
        aaddr[f] = (rr * 128 + ((lane >> 4) << 4)) ^ ((rr & 7) << 4);
        int rn = wc + f * 16 + (lane & 15);
        baddr[f] = (rn * 128 + ((lane >> 4) << 4)) ^ ((rn & 7) << 4);
    }

    f32x4 acc[4][4] = {};

    for (int kt = 0; kt < 16; ++kt) {
        __syncthreads();
#pragma unroll
        for (int r = 0; r < 4; ++r) {
            gload16(Ac + (size_t)(m0 + arow[r]) * (DM * 2) + kt * 128 + akof[r],
                    AsmC + r * 4096 + w * 1024);
            gload16(Bc + (size_t)(n0 + arow[r]) * (DM * 2) + kt * 128 + akof[r],
                    BsmC + r * 4096 + w * 1024);
        }
        __syncthreads();
#pragma unroll
        for (int ks = 0; ks < 2; ++ks) {
            short8 af[4], bf[4];
#pragma unroll
            for (int f = 0; f < 4; ++f) af[f] = *(const short8*)(AsmC + (aaddr[f] ^ (ks << 6)));
#pragma unroll
            for (int f = 0; f < 4; ++f) bf[f] = *(const short8*)(BsmC + (baddr[f] ^ (ks << 6)));
#pragma unroll
            for (int mf = 0; mf < 4; ++mf)
#pragma unroll
                for (int nf = 0; nf < 4; ++nf)
                    acc[mf][nf] = __builtin_amdgcn_mfma_f32_16x16x32_bf16(af[mf], bf[nf], acc[mf][nf], 0, 0, 0);
        }
    }

    if constexpr (MODE == 0) {
        const float* bias = (z == 0) ? bias0 : (z == 1) ? bias1 : bias2;
        const float scl = (z == 0) ? 0.125f : 1.0f;   // fold 1/sqrt(d_k) into Q
        unsigned short* out = ((unsigned short*)outp) + (size_t)z * MROWS * DM;
        float bv[4];
#pragma unroll
        for (int nf = 0; nf < 4; ++nf) bv[nf] = bias[n0 + wc + nf * 16 + (lane & 15)];
#pragma unroll
        for (int mf = 0; mf < 4; ++mf)
#pragma unroll
            for (int nf = 0; nf < 4; ++nf)
#pragma unroll
                for (int i = 0; i < 4; ++i) {
                    int grow = m0 + wr + mf * 16 + ((lane >> 4) << 2) + i;
                    int gcol = n0 + wc + nf * 16 + (lane & 15);
                    float val = (acc[mf][nf][i] + bv[nf]) * scl;
                    int b = grow >> 11, srow = grow & 2047, h = gcol >> 6, e = gcol & 63;
                    out[((size_t)(b * NH + h) * S_LEN + srow) * DH + e] = f2bf(val);
                }
    } else {
        float* out = (float*)outp;
#pragma unroll
        for (int mf = 0; mf < 4; ++mf)
#pragma unroll
            for (int nf = 0; nf < 4; ++nf)
#pragma unroll
                for (int i = 0; i < 4; ++i) {
                    int grow = m0 + wr + mf * 16 + ((lane >> 4) << 2) + i;
                    int gcol = n0 + wc + nf * 16 + (lane & 15);
                    out[(size_t)grow * DM + gcol] = acc[mf][nf][i];
                }
    }
}

// ---------------- flash attention, v3 (swapped QK^T, in-register softmax) ----------------
// grid (32,32) = 1024 blocks (4/CU).  QBLK=64: 4 waves x 16 q-rows.
// S^T = mfma(K, Q): lane holds S[t = kv0+nf*16+(lane>>4)*4+i][q = lane&15] -> full
// q-row per lane; row max/sum = 15 local ops + shfl_xor(16,32).  Defer-max THR=8
// skips O-rescale when __any(pmax-m<=8).  mstate/lstate are per-lane scalars.
// P packed to LDS as 4x b64 (same [q][t] swizzled layout); PV unchanged.
__global__ __launch_bounds__(256, 4) void attn_kernel(
    const unsigned short* __restrict__ Qh, const unsigned short* __restrict__ Kh,
    const unsigned short* __restrict__ Vh, unsigned short* __restrict__ ctx,
    const unsigned int* __restrict__ mbits, const int* __restrict__ flag)
{
    __shared__ __attribute__((aligned(16))) char smem[16384 + 16384 + 8192];
    char* KsmB = smem;            // 2 x 8KB
    char* VsmB = smem + 16384;    // 2 x 8KB
    char* QP   = smem + 32768;    // 8KB: Q stage, then per-wave P (wave w owns [w*2048, +2048))

    const int tid  = threadIdx.x;
    const int w    = tid >> 6;
    const int lane = tid & 63;
    const int q0 = blockIdx.x * 64;
    const int bh = blockIdx.y;

    const char* Qb = (const char*)(Qh + (size_t)bh * S_LEN * DH);
    const char* Kb = (const char*)(Kh + (size_t)bh * S_LEN * DH);
    const char* Vb = (const char*)(Vh + (size_t)bh * S_LEN * DH);

    // ---- stage Q tile (64 x 64 bf16 = 8KB), swizzled; hoist fragments ----
#pragma unroll
    for (int r = 0; r < 2; ++r) {
        int L = r * 4096 + tid * 16;
        int a = L ^ (((L >> 7) & 7) << 4);
        gload16(Qb + (size_t)(q0 + (a >> 7)) * 128 + (a & 127), QP + r * 4096 + w * 1024);
    }
    __syncthreads();
    short8 qf[2];
#pragma unroll
    for (int ks = 0; ks < 2; ++ks) {
        int row = w * 16 + (lane & 15);
        int a = row * 128 + ks * 64 + ((lane >> 4) << 4);
        qf[ks] = *(const short8*)(QP + (a ^ ((row & 7) << 4)));
    }
    __syncthreads();   // Q fully consumed before P reuses the region

    const bool allones = (*flag) != 0;

    float mstate = -INFINITY, lstate = 0.f;
    f32x4 o[4] = {};

    char* Pw = QP + w * 2048;

    // V reg-staging state (t-pair loads held across compute)
    const int vp = tid >> 4;            // pair-slot 0..15
    const int vd0 = (tid & 15) * 4;     // d quad base
    uint2 va[2], vb2[2];

    // ---- prologue: stage kv=0 into buffer 0 ----
#pragma unroll
    for (int r = 0; r < 2; ++r) {
        int L = r * 4096 + tid * 16;
        int a = L ^ (((L >> 7) & 7) << 4);
        gload16(Kb + (size_t)(a >> 7) * 128 + (a & 127), KsmB + r * 4096 + w * 1024);
    }
#pragma unroll
    for (int r = 0; r < 2; ++r) {
        int t0 = (r * 16 + vp) * 2;
        va[r]  = *(const uint2*)(Vb + (size_t)t0 * 128 + vd0 * 2);
        vb2[r] = *(const uint2*)(Vb + (size_t)(t0 + 1) * 128 + vd0 * 2);
    }
#pragma unroll
    for (int r = 0; r < 2; ++r) {
        int pp = r * 16 + vp;
        int d = vd0;
        int vm0 = (d ^ (d >> 3)) & 7;       int vm1 = ((d+1) ^ ((d+1) >> 3)) & 7;
        int vm2 = ((d+2) ^ ((d+2) >> 3)) & 7; int vm3 = ((d+3) ^ ((d+3) >> 3)) & 7;
        *(unsigned int*)(VsmB + (d+0) * 128 + ((pp * 4) ^ (vm0 << 4))) = (va[r].x & 0xffffu) | (vb2[r].x << 16);
        *(unsigned int*)(VsmB + (d+1) * 128 + ((pp * 4) ^ (vm1 << 4))) = (va[r].x >> 16)     | (vb2[r].x & 0xffff0000u);
        *(unsigned int*)(VsmB + (d+2) * 128 + ((pp * 4) ^ (vm2 << 4))) = (va[r].y & 0xffffu) | (vb2[r].y << 16);
        *(unsigned int*)(VsmB + (d+3) * 128 + ((pp * 4) ^ (vm3 << 4))) = (va[r].y >> 16)     | (vb2[r].y & 0xffff0000u);
    }
    __syncthreads();

    for (int kv = 0; kv < 32; ++kv) {
        char* Kc = KsmB + (kv & 1) * 8192;
        char* Vc = VsmB + (kv & 1) * 8192;
        char* Kn = KsmB + ((kv & 1) ^ 1) * 8192;
        char* Vn = VsmB + ((kv & 1) ^ 1) * 8192;
        const bool more = (kv + 1 < 32);
        const int kv0 = kv * 64;

        // ---- issue next tile's loads (hidden under this tile's compute) ----
        if (more) {
            const int kv1 = kv0 + 64;
#pragma unroll
            for (int r = 0; r < 2; ++r) {
                int L = r * 4096 + tid * 16;
                int a = L ^ (((L >> 7) & 7) << 4);
                gload16(Kb + (size_t)(kv1 + (a >> 7)) * 128 + (a & 127), Kn + r * 4096 + w * 1024);
            }
#pragma unroll
            for (int r = 0; r < 2; ++r) {
                int t0 = kv1 + (r * 16 + vp) * 2;
                va[r]  = *(const uint2*)(Vb + (size_t)t0 * 128 + vd0 * 2);
                vb2[r] = *(const uint2*)(Vb + (size_t)(t0 + 1) * 128 + vd0 * 2);
            }
        }

        // ---- S^T = K Q^T (swapped operands; Q pre-scaled by 0.125) ----
        f32x4 sc[4] = {};
#pragma unroll
        for (int ks = 0; ks < 2; ++ks) {
            short8 kf[4];
#pragma unroll
            for (int nf = 0; nf < 4; ++nf) {
                int trow = nf * 16 + (lane & 15);
                int a = trow * 128 + ks * 64 + ((lane >> 4) << 4);
                kf[nf] = *(const short8*)(Kc + (a ^ ((trow & 7) << 4)));
            }
#pragma unroll
            for (int nf = 0; nf < 4; ++nf)
                sc[nf] = __builtin_amdgcn_mfma_f32_16x16x32_bf16(kf[nf], qf[ks], sc[nf], 0, 0, 0);
        }

        // mask (reference order: after scale)
        if (!allones) {
            int row = q0 + w * 16 + (lane & 15);
#pragma unroll
            for (int nf = 0; nf < 4; ++nf)
#pragma unroll
                for (int i = 0; i < 4; ++i) {
                    int t = kv0 + nf * 16 + ((lane >> 4) << 2) + i;
                    if (!((mbits[row * (S_LEN / 32) + (t >> 5)] >> (t & 31)) & 1u))
                        sc[nf][i] = -1e9f;
                }
        }

        // ---- in-register online softmax (lane owns full q-row), defer-max THR=8 ----
        float pmax = sc[0][0];
#pragma unroll
        for (int nf = 0; nf < 4; ++nf)
#pragma unroll
            for (int i = 0; i < 4; ++i) pmax = fmaxf(pmax, sc[nf][i]);
        pmax = fmaxf(pmax, __shfl_xor(pmax, 16));
        pmax = fmaxf(pmax, __shfl_xor(pmax, 32));
        if (__any(pmax - mstate > 8.0f)) {
            float mnew = fmaxf(mstate, pmax);
            float corr = exp2f((mstate - mnew) * LOG2E);
            mstate = mnew;
            lstate *= corr;
#pragma unroll
            for (int i = 0; i < 4; ++i) {
                float ci = __shfl(corr, ((lane >> 4) << 2) + i);
#pragma unroll
                for (int nfo = 0; nfo < 4; ++nfo) o[nfo][i] *= ci;
            }
        }
        float rs = 0.f;
#pragma unroll
        for (int nf = 0; nf < 4; ++nf)
#pragma unroll
            for (int i = 0; i < 4; ++i) {
                float p = exp2f((sc[nf][i] - mstate) * LOG2E);
                sc[nf][i] = p;
                rs += p;
            }
        rs += __shfl_xor(rs, 16);
        rs += __shfl_xor(rs, 32);
        lstate += rs;

        // ---- P -> per-wave LDS: lane writes row q'=lane&15, 4x b64 ----
        {
            int qr = lane & 15;
            int swz = ((qr ^ (qr >> 2)) & 7) << 4;
#pragma unroll
            for (int nf = 0; nf < 4; ++nf) {
                unsigned int lo = (unsigned int)f2bf(sc[nf][0]) | ((unsigned int)f2bf(sc[nf][1]) << 16);
                unsigned int hi = (unsigned int)f2bf(sc[nf][2]) | ((unsigned int)f2bf(sc[nf][3]) << 16);
                int a = qr * 128 + (nf * 16 + ((lane >> 4) << 2)) * 2;
                uint2 pv2; pv2.x = lo; pv2.y = hi;
                *(uint2*)(Pw + (a ^ swz)) = pv2;
            }
        }

        // ---- O += P V ----
#pragma unroll
        for (int ks = 0; ks < 2; ++ks) {
            int prow = lane & 15;
            int ap = prow * 128 + ks * 64 + ((lane >> 4) << 4);
            short8 pa = *(const short8*)(Pw + (ap ^ (((prow ^ (prow >> 2)) & 7) << 4)));
#pragma unroll
            for (int nfo = 0; nfo < 4; ++nfo) {
                int d = nfo * 16 + (lane & 15);
                int vm = (d ^ (d >> 3)) & 7;
                int p0 = ks * 16 + ((lane >> 4) << 2);
                short8 vf = *(const short8*)(Vc + d * 128 + ((p0 * 4) ^ (vm << 4)));
                o[nfo] = __builtin_amdgcn_mfma_f32_16x16x32_bf16(pa, vf, o[nfo], 0, 0, 0);
            }
        }

        // ---- write next V tile into LDS (loads have had a full compute to land) ----
        if (more) {
#pragma unroll
            for (int r = 0; r < 2; ++r) {
                int pp = r * 16 + vp;
                int d = vd0;
                int vm0 = (d ^ (d >> 3)) & 7;       int vm1 = ((d+1) ^ ((d+1) >> 3)) & 7;
                int vm2 = ((d+2) ^ ((d+2) >> 3)) & 7; int vm3 = ((d+3) ^ ((d+3) >> 3)) & 7;
                *(unsigned int*)(Vn + (d+0) * 128 + ((pp * 4) ^ (vm0 << 4))) = (va[r].x & 0xffffu) | (vb2[r].x << 16);
                *(unsigned int*)(Vn + (d+1) * 128 + ((pp * 4) ^ (vm1 << 4))) = (va[r].x >> 16)     | (vb2[r].x & 0xffff0000u);
                *(unsigned int*)(Vn + (d+2) * 128 + ((pp * 4) ^ (vm2 << 4))) = (va[r].y & 0xffffu) | (vb2[r].y << 16);
                *(unsigned int*)(Vn + (d+3) * 128 + ((pp * 4) ^ (vm3 << 4))) = (va[r].y >> 16)     | (vb2[r].y & 0xffff0000u);
            }
        }
        __syncthreads();
    }

    // ---- epilogue: redistribute lstate to o-layout, normalize, write ----
    const int b = bh >> 4;
    const int h = bh & 15;
    float li[4];
#pragma unroll
    for (int i = 0; i < 4; ++i) li[i] = __shfl(lstate, ((lane >> 4) << 2) + i);
#pragma unroll
    for (int nfo = 0; nfo < 4; ++nfo)
#pragma unroll
        for (int i = 0; i < 4; ++i) {
            int srow = q0 + w * 16 + ((lane >> 4) << 2) + i;
            int e = nfo * 16 + (lane & 15);
            float val = o[nfo][i] / li[i];
            ctx[((size_t)(b * S_LEN + srow)) * DM + h * DH + e] = f2bf(val);
        }
}

// ---------------- launcher ----------------
extern "C" void kernel_launch(void* const* d_in, const int* in_sizes, int n_in,
                              void* d_out, int out_size, void* d_ws, size_t ws_size,
                              hipStream_t stream)
{
    const float* q    = (const float*)d_in[0];
    const float* k    = (const float*)d_in[1];
    const float* v    = (const float*)d_in[2];
    const int*   mask = (const int*)d_in[3];
    const float* Wq   = (const float*)d_in[4];
    const float* bq   = (const float*)d_in[5];
    const float* Wk   = (const float*)d_in[6];
    const float* bk   = (const float*)d_in[7];
    const float* Wv   = (const float*)d_in[8];
    const float* bv   = (const float*)d_in[9];
    const float* Wo   = (const float*)d_in[10];

    // workspace layout (ctx aliases qkvb: qkvb dead after gemm<0>, ctx written by attn)
    char* W = (char*)d_ws;
    unsigned short* qkvb = (unsigned short*)(W + 0);           // 3 x 4194304 bf16 (25165824 B)
    unsigned short* ctx  = (unsigned short*)(W + 0);           // 4194304 bf16, aliases qkvb
    unsigned short* Wt   = (unsigned short*)(W + 25165824);    // 3 x 1048576 bf16 (6291456 B)
    unsigned short* QKVh = (unsigned short*)(W + 31457280);    // 3 x 4194304 bf16 (25165824 B)
    unsigned short* Wot  = (unsigned short*)(W + 56623104);    // 1048576 bf16 (2097152 B)
    unsigned int*   mbits= (unsigned int*)(W + 58720256);      // 524288 B
    int*            flag = (int*)(W + 59244544);               // 4 B
    if (ws_size < (size_t)59244548) return;                    // ws too small -> visible failure

    initflag_kernel<<<1, 64, 0, stream>>>(flag);
    convert3<<<4096, 256, 0, stream>>>(q, k, v, qkvb, qkvb + 4194304, qkvb + 8388608, 1048576);
    transpose_bf16<<<dim3(32, 2, 16), 256, 0, stream>>>(Wq, Wt,            1024, 64);
    transpose_bf16<<<dim3(32, 2, 16), 256, 0, stream>>>(Wk, Wt + 1048576,  1024, 64);
    transpose_bf16<<<dim3(32, 2, 16), 256, 0, stream>>>(Wv, Wt + 2097152,  1024, 64);
    transpose_bf16<<<dim3(32, 32, 1), 256, 0, stream>>>(Wo, Wot,           1024, 1024);
    maskbits_kernel<<<512, 256, 0, stream>>>(mask, mbits, flag);
    gemm128<0><<<dim3(8, 32, 3), 256, 0, stream>>>(qkvb, Wt, bq, bk, bv, (void*)QKVh);
    attn_kernel<<<dim3(32, 32), 256, 0, stream>>>(QKVh, QKVh + 4194304, QKVh + 8388608, ctx, mbits, flag);
    gemm128<1><<<dim3(8, 32, 1), 256, 0, stream>>>(ctx, Wot, nullptr, nullptr, nullptr, d_out);
}

// Round 10
// 288.994 us; speedup vs baseline: 1.4643x; 1.0367x over previous
//
#include <hip/hip_runtime.h>
#include <math.h>

// ---------------- constants for this problem ----------------
#define S_LEN 2048
#define DM    1024
#define NH    16
#define DH    64
#define BATCH 2
#define MROWS 4096        // BATCH * S_LEN
#define LOG2E 1.44269504088896340736f

typedef __attribute__((ext_vector_type(8))) short short8;   // 8 x bf16 (4 VGPRs)
typedef __attribute__((ext_vector_type(4))) float f32x4;

// fp32 -> bf16 round-to-nearest-even (finite inputs)
__device__ __forceinline__ unsigned short f2bf(float f) {
    unsigned int u = __float_as_uint(f);
    u += 0x7FFFu + ((u >> 16) & 1u);
    return (unsigned short)(u >> 16);
}

// pack two f32 -> u32 of 2 bf16 (RTNE), single instruction (T12 recipe)
__device__ __forceinline__ unsigned int cvtpk(float lo, float hi) {
    unsigned int r;
    asm("v_cvt_pk_bf16_f32 %0, %1, %2" : "=v"(r) : "v"(lo), "v"(hi));
    return r;
}

// interleave low/high halves of two u32s holding bf16 pairs
__device__ __forceinline__ unsigned int perm_lo(unsigned int va, unsigned int vb) {
    return __builtin_amdgcn_perm(vb, va, 0x05040100);   // (va&0xffff)|(vb<<16)
}
__device__ __forceinline__ unsigned int perm_hi(unsigned int va, unsigned int vb) {
    return __builtin_amdgcn_perm(vb, va, 0x07060302);   // (va>>16)|(vb&0xffff0000)
}

// async global->LDS, 16B per lane; LDS dest = wave-uniform base + lane*16
__device__ __forceinline__ void gload16(const void* g, void* lds) {
    __builtin_amdgcn_global_load_lds((const __attribute__((address_space(1))) void*)g,
                                     (__attribute__((address_space(3))) void*)lds,
                                     16, 0, 0);
}

// ---------------- small prep kernels ----------------
__global__ void initflag_kernel(int* flag) {
    if (threadIdx.x == 0 && blockIdx.x == 0) *flag = 1;
}

__global__ __launch_bounds__(256) void convert3(
    const float* __restrict__ q, const float* __restrict__ k, const float* __restrict__ v,
    unsigned short* __restrict__ qb, unsigned short* __restrict__ kb, unsigned short* __restrict__ vb,
    int n4)
{
    int i = blockIdx.x * 256 + threadIdx.x;
    if (i >= n4) return;
    float4 a = ((const float4*)q)[i];
    float4 b = ((const float4*)k)[i];
    float4 c = ((const float4*)v)[i];
    ((ushort4*)qb)[i] = make_ushort4(f2bf(a.x), f2bf(a.y), f2bf(a.z), f2bf(a.w));
    ((ushort4*)kb)[i] = make_ushort4(f2bf(b.x), f2bf(b.y), f2bf(b.z), f2bf(b.w));
    ((ushort4*)vb)[i] = make_ushort4(f2bf(c.x), f2bf(c.y), f2bf(c.z), f2bf(c.w));
}

// transpose [R][C] fp32 slab -> [C][R] bf16 slab (slab = blockIdx.z * R * C for both)
__global__ __launch_bounds__(256) void transpose_bf16(
    const float* __restrict__ in, unsigned short* __restrict__ out, int R, int C)
{
    __shared__ float tile[32][33];
    const size_t slab = (size_t)blockIdx.z * R * C;
    const int r0 = blockIdx.x * 32;
    const int c0 = blockIdx.y * 32;
    const int tr = threadIdx.x >> 5;
    const int tc = threadIdx.x & 31;
#pragma unroll
    for (int j = 0; j < 32; j += 8)
        tile[tr + j][tc] = in[slab + (size_t)(r0 + tr + j) * C + c0 + tc];
    __syncthreads();
#pragma unroll
    for (int j = 0; j < 32; j += 8)
        out[slab + (size_t)(c0 + tr + j) * R + r0 + tc] = f2bf(tile[tc][tr + j]);
}

// mask[S*S] int32 -> bit per element; flag &= all-ones
__global__ __launch_bounds__(256) void maskbits_kernel(
    const int* __restrict__ mask, unsigned int* __restrict__ bits, int* __restrict__ flag)
{
    int widx = blockIdx.x * 256 + threadIdx.x;      // word index, 131072 total
    const int4* src = (const int4*)(mask + (size_t)widx * 32);
    unsigned int wb = 0;
#pragma unroll
    for (int j = 0; j < 8; ++j) {
        int4 vv = src[j];
        wb |= (vv.x != 0 ? 1u : 0u) << (4 * j);
        wb |= (vv.y != 0 ? 1u : 0u) << (4 * j + 1);
        wb |= (vv.z != 0 ? 1u : 0u) << (4 * j + 2);
        wb |= (vv.w != 0 ? 1u : 0u) << (4 * j + 3);
    }
    bits[widx] = wb;
    if (wb != 0xFFFFFFFFu) atomicAnd(flag, 0);
}

// ---------------- 128x128 bf16 GEMM (K=1024 fixed), m97-style ----------------
// MODE 0: out = bf16, (acc+bias)*0.125 for z==0 (attn scale folded into Q), scattered
//         to [B][H][S][64] head-major.  MODE 1: out = fp32 row-major (d_out).
template<int MODE>
__global__ __launch_bounds__(256) void gemm128(
    const unsigned short* __restrict__ Aall,
    const unsigned short* __restrict__ Btall,
    const float* __restrict__ bias0, const float* __restrict__ bias1, const float* __restrict__ bias2,
    void* __restrict__ outp)
{
    __shared__ __attribute__((aligned(16))) unsigned short Asm[128 * 64];
    __shared__ __attribute__((aligned(16))) unsigned short Bsm[128 * 64];
    char* AsmC = (char*)Asm;
    char* BsmC = (char*)Bsm;
    const int tid  = threadIdx.x;
    const int w    = tid >> 6;
    const int lane = tid & 63;
    const int m0 = blockIdx.y * 128;
    const int n0 = blockIdx.x * 128;
    const int z  = blockIdx.z;

    const char* Ac = (const char*)(Aall + (size_t)z * MROWS * DM);
    const char* Bc = (const char*)(Btall + (size_t)z * DM * DM);

    int arow[4], akof[4];
#pragma unroll
    for (int r = 0; r < 4; ++r) {
        int L = r * 4096 + tid * 16;
        int a = L ^ (((L >> 7) & 7) << 4);
        arow[r] = a >> 7;
        akof[r] = a & 127;
    }

    const int wr = (w >> 1) * 64;
    const int wc = (w & 1) * 64;
    int aaddr[4], baddr[4];
#pragma unroll
    for (int f = 0; f < 4; ++f) {
        int rr = wr + f * 16 + (lane & 15);
        aaddr[f] = (rr * 128 + ((lane >> 4) << 4)) ^ ((rr & 7) << 4);
        int rn = wc + f * 16 + (lane & 15);
        baddr[f] = (rn * 128 + ((lane >> 4) << 4)) ^ ((rn & 7) << 4);
    }

    f32x4 acc[4][4] = {};

    for (int kt = 0; kt < 16; ++kt) {
        __syncthreads();
#pragma unroll
        for (int r = 0; r < 4; ++r) {
            gload16(Ac + (size_t)(m0 + arow[r]) * (DM * 2) + kt * 128 + akof[r],
                    AsmC + r * 4096 + w * 1024);
            gload16(Bc + (size_t)(n0 + arow[r]) * (DM * 2) + kt * 128 + akof[r],
                    BsmC + r * 4096 + w * 1024);
        }
        __syncthreads();
#pragma unroll
        for (int ks = 0; ks < 2; ++ks) {
            short8 af[4], bf[4];
#pragma unroll
            for (int f = 0; f < 4; ++f) af[f] = *(const short8*)(AsmC + (aaddr[f] ^ (ks << 6)));
#pragma unroll
            for (int f = 0; f < 4; ++f) bf[f] = *(const short8*)(BsmC + (baddr[f] ^ (ks << 6)));
#pragma unroll
            for (int mf = 0; mf < 4; ++mf)
#pragma unroll
                for (int nf = 0; nf < 4; ++nf)
                    acc[mf][nf] = __builtin_amdgcn_mfma_f32_16x16x32_bf16(af[mf], bf[nf], acc[mf][nf], 0, 0, 0);
        }
    }

    if constexpr (MODE == 0) {
        const float* bias = (z == 0) ? bias0 : (z == 1) ? bias1 : bias2;
        const float scl = (z == 0) ? 0.125f : 1.0f;   // fold 1/sqrt(d_k) into Q
        unsigned short* out = ((unsigned short*)outp) + (size_t)z * MROWS * DM;
        float bv[4];
#pragma unroll
        for (int nf = 0; nf < 4; ++nf) bv[nf] = bias[n0 + wc + nf * 16 + (lane & 15)];
#pragma unroll
        for (int mf = 0; mf < 4; ++mf)
#pragma unroll
            for (int nf = 0; nf < 4; ++nf)
#pragma unroll
                for (int i = 0; i < 4; ++i) {
                    int grow = m0 + wr + mf * 16 + ((lane >> 4) << 2) + i;
                    int gcol = n0 + wc + nf * 16 + (lane & 15);
                    float val = (acc[mf][nf][i] + bv[nf]) * scl;
                    int b = grow >> 11, srow = grow & 2047, h = gcol >> 6, e = gcol & 63;
                    out[((size_t)(b * NH + h) * S_LEN + srow) * DH + e] = f2bf(val);
                }
    } else {
        float* out = (float*)outp;
#pragma unroll
        for (int mf = 0; mf < 4; ++mf)
#pragma unroll
            for (int nf = 0; nf < 4; ++nf)
#pragma unroll
                for (int i = 0; i < 4; ++i) {
                    int grow = m0 + wr + mf * 16 + ((lane >> 4) << 2) + i;
                    int gcol = n0 + wc + nf * 16 + (lane & 15);
                    out[(size_t)grow * DM + gcol] = acc[mf][nf][i];
                }
    }
}

// ---------------- flash attention, v4 (v3 + cvt_pk P-pack + perm V-pack) ----------------
// grid (32,32) = 1024 blocks (4/CU).  QBLK=64: 4 waves x 16 q-rows.
// S^T = mfma(K, Q): lane holds S[t][q=lane&15] -> full q-row per lane; row max/sum =
// 15 local ops + shfl_xor(16,32).  Defer-max THR=8.  P pack via v_cvt_pk_bf16_f32.
__global__ __launch_bounds__(256, 4) void attn_kernel(
    const unsigned short* __restrict__ Qh, const unsigned short* __restrict__ Kh,
    const unsigned short* __restrict__ Vh, unsigned short* __restrict__ ctx,
    const unsigned int* __restrict__ mbits, const int* __restrict__ flag)
{
    __shared__ __attribute__((aligned(16))) char smem[16384 + 16384 + 8192];
    char* KsmB = smem;            // 2 x 8KB
    char* VsmB = smem + 16384;    // 2 x 8KB
    char* QP   = smem + 32768;    // 8KB: Q stage, then per-wave P (wave w owns [w*2048, +2048))

    const int tid  = threadIdx.x;
    const int w    = tid >> 6;
    const int lane = tid & 63;
    const int q0 = blockIdx.x * 64;
    const int bh = blockIdx.y;

    const char* Qb = (const char*)(Qh + (size_t)bh * S_LEN * DH);
    const char* Kb = (const char*)(Kh + (size_t)bh * S_LEN * DH);
    const char* Vb = (const char*)(Vh + (size_t)bh * S_LEN * DH);

    // ---- stage Q tile (64 x 64 bf16 = 8KB), swizzled; hoist fragments ----
#pragma unroll
    for (int r = 0; r < 2; ++r) {
        int L = r * 4096 + tid * 16;
        int a = L ^ (((L >> 7) & 7) << 4);
        gload16(Qb + (size_t)(q0 + (a >> 7)) * 128 + (a & 127), QP + r * 4096 + w * 1024);
    }
    __syncthreads();
    short8 qf[2];
#pragma unroll
    for (int ks = 0; ks < 2; ++ks) {
        int row = w * 16 + (lane & 15);
        int a = row * 128 + ks * 64 + ((lane >> 4) << 4);
        qf[ks] = *(const short8*)(QP + (a ^ ((row & 7) << 4)));
    }
    __syncthreads();   // Q fully consumed before P reuses the region

    const bool allones = (*flag) != 0;

    float mstate = -INFINITY, lstate = 0.f;
    f32x4 o[4] = {};

    char* Pw = QP + w * 2048;

    // V reg-staging state (t-pair loads held across compute)
    const int vp = tid >> 4;            // pair-slot 0..15
    const int vd0 = (tid & 15) * 4;     // d quad base
    uint2 va[2], vb2[2];

    // ---- prologue: stage kv=0 into buffer 0 ----
#pragma unroll
    for (int r = 0; r < 2; ++r) {
        int L = r * 4096 + tid * 16;
        int a = L ^ (((L >> 7) & 7) << 4);
        gload16(Kb + (size_t)(a >> 7) * 128 + (a & 127), KsmB + r * 4096 + w * 1024);
    }
#pragma unroll
    for (int r = 0; r < 2; ++r) {
        int t0 = (r * 16 + vp) * 2;
        va[r]  = *(const uint2*)(Vb + (size_t)t0 * 128 + vd0 * 2);
        vb2[r] = *(const uint2*)(Vb + (size_t)(t0 + 1) * 128 + vd0 * 2);
    }
#pragma unroll
    for (int r = 0; r < 2; ++r) {
        int pp = r * 16 + vp;
        int d = vd0;
        int vm0 = (d ^ (d >> 3)) & 7;       int vm1 = ((d+1) ^ ((d+1) >> 3)) & 7;
        int vm2 = ((d+2) ^ ((d+2) >> 3)) & 7; int vm3 = ((d+3) ^ ((d+3) >> 3)) & 7;
        *(unsigned int*)(VsmB + (d+0) * 128 + ((pp * 4) ^ (vm0 << 4))) = perm_lo(va[r].x, vb2[r].x);
        *(unsigned int*)(VsmB + (d+1) * 128 + ((pp * 4) ^ (vm1 << 4))) = perm_hi(va[r].x, vb2[r].x);
        *(unsigned int*)(VsmB + (d+2) * 128 + ((pp * 4) ^ (vm2 << 4))) = perm_lo(va[r].y, vb2[r].y);
        *(unsigned int*)(VsmB + (d+3) * 128 + ((pp * 4) ^ (vm3 << 4))) = perm_hi(va[r].y, vb2[r].y);
    }
    __syncthreads();

    for (int kv = 0; kv < 32; ++kv) {
        char* Kc = KsmB + (kv & 1) * 8192;
        char* Vc = VsmB + (kv & 1) * 8192;
        char* Kn = KsmB + ((kv & 1) ^ 1) * 8192;
        char* Vn = VsmB + ((kv & 1) ^ 1) * 8192;
        const bool more = (kv + 1 < 32);
        const int kv0 = kv * 64;

        // ---- issue next tile's loads (hidden under this tile's compute) ----
        if (more) {
            const int kv1 = kv0 + 64;
#pragma unroll
            for (int r = 0; r < 2; ++r) {
                int L = r * 4096 + tid * 16;
                int a = L ^ (((L >> 7) & 7) << 4);
                gload16(Kb + (size_t)(kv1 + (a >> 7)) * 128 + (a & 127), Kn + r * 4096 + w * 1024);
            }
#pragma unroll
            for (int r = 0; r < 2; ++r) {
                int t0 = kv1 + (r * 16 + vp) * 2;
                va[r]  = *(const uint2*)(Vb + (size_t)t0 * 128 + vd0 * 2);
                vb2[r] = *(const uint2*)(Vb + (size_t)(t0 + 1) * 128 + vd0 * 2);
            }
        }

        // ---- S^T = K Q^T (swapped operands; Q pre-scaled by 0.125) ----
        f32x4 sc[4] = {};
#pragma unroll
        for (int ks = 0; ks < 2; ++ks) {
            short8 kf[4];
#pragma unroll
            for (int nf = 0; nf < 4; ++nf) {
                int trow = nf * 16 + (lane & 15);
                int a = trow * 128 + ks * 64 + ((lane >> 4) << 4);
                kf[nf] = *(const short8*)(Kc + (a ^ ((trow & 7) << 4)));
            }
#pragma unroll
            for (int nf = 0; nf < 4; ++nf)
                sc[nf] = __builtin_amdgcn_mfma_f32_16x16x32_bf16(kf[nf], qf[ks], sc[nf], 0, 0, 0);
        }

        // mask (reference order: after scale)
        if (!allones) {
            int row = q0 + w * 16 + (lane & 15);
#pragma unroll
            for (int nf = 0; nf < 4; ++nf)
#pragma unroll
                for (int i = 0; i < 4; ++i) {
                    int t = kv0 + nf * 16 + ((lane >> 4) << 2) + i;
                    if (!((mbits[row * (S_LEN / 32) + (t >> 5)] >> (t & 31)) & 1u))
                        sc[nf][i] = -1e9f;
                }
        }

        // ---- in-register online softmax (lane owns full q-row), defer-max THR=8 ----
        float pmax = sc[0][0];
#pragma unroll
        for (int nf = 0; nf < 4; ++nf)
#pragma unroll
            for (int i = 0; i < 4; ++i) pmax = fmaxf(pmax, sc[nf][i]);
        pmax = fmaxf(pmax, __shfl_xor(pmax, 16));
        pmax = fmaxf(pmax, __shfl_xor(pmax, 32));
        if (__any(pmax - mstate > 8.0f)) {
            float mnew = fmaxf(mstate, pmax);
            float corr = exp2f((mstate - mnew) * LOG2E);
            mstate = mnew;
            lstate *= corr;
#pragma unroll
            for (int i = 0; i < 4; ++i) {
                float ci = __shfl(corr, ((lane >> 4) << 2) + i);
#pragma unroll
                for (int nfo = 0; nfo < 4; ++nfo) o[nfo][i] *= ci;
            }
        }
        float rs = 0.f;
#pragma unroll
        for (int nf = 0; nf < 4; ++nf)
#pragma unroll
            for (int i = 0; i < 4; ++i) {
                float p = exp2f((sc[nf][i] - mstate) * LOG2E);
                sc[nf][i] = p;
                rs += p;
            }
        rs += __shfl_xor(rs, 16);
        rs += __shfl_xor(rs, 32);
        lstate += rs;

        // ---- P -> per-wave LDS: lane writes row q'=lane&15, 4x b64 via cvt_pk ----
        {
            int qr = lane & 15;
            int swz = ((qr ^ (qr >> 2)) & 7) << 4;
#pragma unroll
            for (int nf = 0; nf < 4; ++nf) {
                uint2 pv2;
                pv2.x = cvtpk(sc[nf][0], sc[nf][1]);
                pv2.y = cvtpk(sc[nf][2], sc[nf][3]);
                int a = qr * 128 + (nf * 16 + ((lane >> 4) << 2)) * 2;
                *(uint2*)(Pw + (a ^ swz)) = pv2;
            }
        }

        // ---- O += P V ----
#pragma unroll
        for (int ks = 0; ks < 2; ++ks) {
            int prow = lane & 15;
            int ap = prow * 128 + ks * 64 + ((lane >> 4) << 4);
            short8 pa = *(const short8*)(Pw + (ap ^ (((prow ^ (prow >> 2)) & 7) << 4)));
#pragma unroll
            for (int nfo = 0; nfo < 4; ++nfo) {
                int d = nfo * 16 + (lane & 15);
                int vm = (d ^ (d >> 3)) & 7;
                int p0 = ks * 16 + ((lane >> 4) << 2);
                short8 vf = *(const short8*)(Vc + d * 128 + ((p0 * 4) ^ (vm << 4)));
                o[nfo] = __builtin_amdgcn_mfma_f32_16x16x32_bf16(pa, vf, o[nfo], 0, 0, 0);
            }
        }

        // ---- write next V tile into LDS (loads have had a full compute to land) ----
        if (more) {
#pragma unroll
            for (int r = 0; r < 2; ++r) {
                int pp = r * 16 + vp;
                int d = vd0;
                int vm0 = (d ^ (d >> 3)) & 7;       int vm1 = ((d+1) ^ ((d+1) >> 3)) & 7;
                int vm2 = ((d+2) ^ ((d+2) >> 3)) & 7; int vm3 = ((d+3) ^ ((d+3) >> 3)) & 7;
                *(unsigned int*)(Vn + (d+0) * 128 + ((pp * 4) ^ (vm0 << 4))) = perm_lo(va[r].x, vb2[r].x);
                *(unsigned int*)(Vn + (d+1) * 128 + ((pp * 4) ^ (vm1 << 4))) = perm_hi(va[r].x, vb2[r].x);
                *(unsigned int*)(Vn + (d+2) * 128 + ((pp * 4) ^ (vm2 << 4))) = perm_lo(va[r].y, vb2[r].y);
                *(unsigned int*)(Vn + (d+3) * 128 + ((pp * 4) ^ (vm3 << 4))) = perm_hi(va[r].y, vb2[r].y);
            }
        }
        __syncthreads();
    }

    // ---- epilogue: redistribute lstate to o-layout, normalize, write ----
    const int b = bh >> 4;
    const int h = bh & 15;
    float li[4];
#pragma unroll
    for (int i = 0; i < 4; ++i) li[i] = __shfl(lstate, ((lane >> 4) << 2) + i);
#pragma unroll
    for (int nfo = 0; nfo < 4; ++nfo)
#pragma unroll
        for (int i = 0; i < 4; ++i) {
            int srow = q0 + w * 16 + ((lane >> 4) << 2) + i;
            int e = nfo * 16 + (lane & 15);
            float val = o[nfo][i] / li[i];
            ctx[((size_t)(b * S_LEN + srow)) * DM + h * DH + e] = f2bf(val);
        }
}

// ---------------- launcher ----------------
extern "C" void kernel_launch(void* const* d_in, const int* in_sizes, int n_in,
                              void* d_out, int out_size, void* d_ws, size_t ws_size,
                              hipStream_t stream)
{
    const float* q    = (const float*)d_in[0];
    const float* k    = (const float*)d_in[1];
    const float* v    = (const float*)d_in[2];
    const int*   mask = (const int*)d_in[3];
    const float* Wq   = (const float*)d_in[4];
    const float* bq   = (const float*)d_in[5];
    const float* Wk   = (const float*)d_in[6];
    const float* bk   = (const float*)d_in[7];
    const float* Wv   = (const float*)d_in[8];
    const float* bv   = (const float*)d_in[9];
    const float* Wo   = (const float*)d_in[10];

    // workspace layout (ctx aliases qkvb: qkvb dead after gemm<0>, ctx written by attn)
    char* W = (char*)d_ws;
    unsigned short* qkvb = (unsigned short*)(W + 0);           // 3 x 4194304 bf16 (25165824 B)
    unsigned short* ctx  = (unsigned short*)(W + 0);           // 4194304 bf16, aliases qkvb
    unsigned short* Wt   = (unsigned short*)(W + 25165824);    // 3 x 1048576 bf16 (6291456 B)
    unsigned short* QKVh = (unsigned short*)(W + 31457280);    // 3 x 4194304 bf16 (25165824 B)
    unsigned short* Wot  = (unsigned short*)(W + 56623104);    // 1048576 bf16 (2097152 B)
    unsigned int*   mbits= (unsigned int*)(W + 58720256);      // 524288 B
    int*            flag = (int*)(W + 59244544);               // 4 B
    if (ws_size < (size_t)59244548) return;                    // ws too small -> visible failure

    initflag_kernel<<<1, 64, 0, stream>>>(flag);
    convert3<<<4096, 256, 0, stream>>>(q, k, v, qkvb, qkvb + 4194304, qkvb + 8388608, 1048576);
    transpose_bf16<<<dim3(32, 2, 16), 256, 0, stream>>>(Wq, Wt,            1024, 64);
    transpose_bf16<<<dim3(32, 2, 16), 256, 0, stream>>>(Wk, Wt + 1048576,  1024, 64);
    transpose_bf16<<<dim3(32, 2, 16), 256, 0, stream>>>(Wv, Wt + 2097152,  1024, 64);
    transpose_bf16<<<dim3(32, 32, 1), 256, 0, stream>>>(Wo, Wot,           1024, 1024);
    maskbits_kernel<<<512, 256, 0, stream>>>(mask, mbits, flag);
    gemm128<0><<<dim3(8, 32, 3), 256, 0, stream>>>(qkvb, Wt, bq, bk, bv, (void*)QKVh);
    attn_kernel<<<dim3(32, 32), 256, 0, stream>>>(QKVh, QKVh + 4194304, QKVh + 8388608, ctx, mbits, flag);
    gemm128<1><<<dim3(8, 32, 1), 256, 0, stream>>>(ctx, Wot, nullptr, nullptr, nullptr, d_out);
}